// Round 4
// baseline (416.638 us; speedup 1.0000x reference)
//
#include <hip/hip_runtime.h>
#include <stdint.h>

// Problem constants
#define B_  2
#define T_  2048
#define C_  2048
#define H_  16
#define D_  128
#define BH_ 32        // B*H
#define M_  4096      // B*T

typedef __attribute__((ext_vector_type(8))) __bf16  bf16x8;
typedef __attribute__((ext_vector_type(4))) float   floatx4;
typedef __attribute__((ext_vector_type(4))) ushort  ushortx4;
typedef __attribute__((ext_vector_type(8))) ushort  ushortx8;

__device__ __forceinline__ ushort f2bf(float f) {
    union { float f; uint32_t u; } v; v.f = f;
    return (ushort)((v.u + 0x7fffu + ((v.u >> 16) & 1u)) >> 16);
}

__device__ __forceinline__ float bf2f(ushort u) {
    union { uint32_t u; float f; } v; v.u = ((uint32_t)u) << 16;
    return v.f;
}

__device__ __forceinline__ floatx4 mfma_bf16(bf16x8 a, bf16x8 b, floatx4 c) {
    return __builtin_amdgcn_mfma_f32_16x16x32_bf16(a, b, c, 0, 0, 0);
}

// async global->LDS, 16B per lane; lds dest = wave-uniform base + lane*16
__device__ __forceinline__ void async16(const ushort* g, ushort* l) {
    __builtin_amdgcn_global_load_lds(
        (const __attribute__((address_space(1))) uint32_t*)g,
        (__attribute__((address_space(3))) uint32_t*)l, 16, 0, 0);
}

// ---------------------------------------------------------------------------
// x f32 -> bf16 (vectorized 4-wide)
// ---------------------------------------------------------------------------
__global__ __launch_bounds__(256) void convert_bf16(
    const float* __restrict__ X, ushort* __restrict__ Xb)
{
    const int i = blockIdx.x * 256 + threadIdx.x;
    const float4 v = ((const float4*)X)[i];
    ushortx4 p = { f2bf(v.x), f2bf(v.y), f2bf(v.z), f2bf(v.w) };
    ((ushortx4*)Xb)[i] = p;
}

// ---------------------------------------------------------------------------
// Transpose + convert: W f32 [K][N] -> Wt bf16 [N][K]
// ---------------------------------------------------------------------------
__global__ __launch_bounds__(256) void transpose_w(
    const float* __restrict__ W, ushort* __restrict__ Wt, int Kdim, int Ndim)
{
    __shared__ float tile[32][33];
    const int n0 = blockIdx.x * 32, k0 = blockIdx.y * 32;
    const int tx = threadIdx.x, ty = threadIdx.y;
    #pragma unroll
    for (int j = 0; j < 4; j++)
        tile[ty + j*8][tx] = W[(size_t)(k0 + ty + j*8) * Ndim + n0 + tx];
    __syncthreads();
    #pragma unroll
    for (int j = 0; j < 4; j++)
        Wt[(size_t)(n0 + ty + j*8) * Kdim + k0 + tx] = f2bf(tile[tx][ty + j*8]);
}

// ---------------------------------------------------------------------------
// Shared 2-barrier 256x256 K-loop, BK=64, 512 threads = 8 waves (2M x 4N).
//   Per-wave output 128x64. LDS 2dbuf x (A 32KB + B 32KB) = 128 KiB.
//   XOR-swizzle unit ^= row&7 on BOTH sides (pre-swizzled global_load_lds
//   source + swizzled ds_read) per rule #21; LDS dest linear.
//
//   ONE barrier pair per K-tile (R1's 8 barriers/K-tile serialized LDS
//   reads against MFMA -> 6600 cyc/iter, MfmaUtil 23%). All fragment reads
//   of buffer p are legal at iteration start (buffer stable the whole
//   iteration); stages into buffer p (tile t+2, same parity) are legal
//   after ONE barrier certifying all waves finished reading. Body is
//   barrier-free so the 8 waves stagger and LDS-read traffic overlaps the
//   per-CU matrix pipe.
//
//   iter t:  reads fa(m0),fb0 -> lgkm0 -> q00
//            reads fb1        -> lgkm0 -> q01
//            reads fa(m1)     -> lgkm0 -> q10,q11   (fa regs reused)
//            barrier                                 (buf p all-dead)
//            stage 8 blocks of tile t+2 -> buf p
//            vmcnt(8)                                (tile t+1 resident)
//            barrier                                 (t+1 published)
//   vmcnt ledger: outstanding at vmcnt = t+1's 8 + t+2's 8 = 16 ->
//   vmcnt(8) retires exactly tile t+1 (FIFO). Tail t>=30 drains vmcnt(0).
//   Every waitcnt asm is followed by sched_barrier(0) (rule #18).
// ---------------------------------------------------------------------------
struct FragA { bf16x8 f[4][2]; };
struct FragB { bf16x8 f[2][2]; };

__device__ __forceinline__ void load_a(FragA& fa, const ushort* Ab, int base,
                                       int lr, int quad)
{
    #pragma unroll
    for (int mi2 = 0; mi2 < 4; mi2++)
        #pragma unroll
        for (int kk = 0; kk < 2; kk++) {
            const int row = base + mi2 * 16 + lr;
            fa.f[mi2][kk] = *(const bf16x8*)(
                Ab + row * 64 + (((kk * 4 + quad) ^ (lr & 7)) << 3));
        }
}

__device__ __forceinline__ void load_b(FragB& fb, const ushort* Bb, int base,
                                       int lr, int quad)
{
    #pragma unroll
    for (int ni2 = 0; ni2 < 2; ni2++)
        #pragma unroll
        for (int kk = 0; kk < 2; kk++) {
            const int row = base + ni2 * 16 + lr;
            fb.f[ni2][kk] = *(const bf16x8*)(
                Bb + row * 64 + (((kk * 4 + quad) ^ (lr & 7)) << 3));
        }
}

__device__ __forceinline__ void mfma_quad(floatx4 (&acc)[8][4], const FragA& fa,
                                          const FragB& fb, int mh, int nh)
{
    #pragma unroll
    for (int mi2 = 0; mi2 < 4; mi2++)
        #pragma unroll
        for (int ni2 = 0; ni2 < 2; ni2++)
            #pragma unroll
            for (int kk = 0; kk < 2; kk++)
                acc[mh*4 + mi2][nh*2 + ni2] =
                    mfma_bf16(fa.f[mi2][kk], fb.f[ni2][kk],
                              acc[mh*4 + mi2][nh*2 + ni2]);
}

// stage one 64-row x 64-col block (blk in 0..3) of a [256][2048] bf16 panel
// into LDS (linear dest, inverse-swizzled global source: unit ^= row&7)
__device__ __forceinline__ void stage64(const ushort* __restrict__ gsrc,
                                        ushort* ldst, int blk, int k0, int tid)
{
    const int lane = tid & 63;
    const int w8   = tid >> 6;            // wave id, uniform
    const int rl   = lane >> 3;           // 0..7 (== row&7)
    const int u    = lane & 7;
    const int row  = (blk << 6) + (w8 << 3) + rl;
    const ushort* g = gsrc + (size_t)row * C_ + k0 + ((u ^ rl) << 3);
    async16(g, ldst + (blk << 12) + (w8 << 9));   // wave-uniform LDS base
}

__device__ __forceinline__ void kloop(
    const ushort* __restrict__ Ablk, const ushort* __restrict__ Bblk,
    ushort* lds, floatx4 (&acc)[8][4], int tid)
{
    const int lane = tid & 63;
    const int w    = tid >> 6;
    const int wr   = w >> 2;               // 0..1
    const int wc   = w & 3;                // 0..3
    const int lr   = lane & 15;
    const int quad = lane >> 4;

    // ---- prologue: stage K-tiles 0 (buf0) and 1 (buf1) ----
    #pragma unroll
    for (int blk = 0; blk < 4; blk++) {
        stage64(Ablk, lds,         blk, 0, tid);
        stage64(Bblk, lds + 32768, blk, 0, tid);
    }
    #pragma unroll
    for (int blk = 0; blk < 4; blk++) {
        stage64(Ablk, lds + 16384, blk, 64, tid);
        stage64(Bblk, lds + 49152, blk, 64, tid);
    }
    asm volatile("s_waitcnt vmcnt(8)" ::: "memory");   // tile 0 resident
    __builtin_amdgcn_sched_barrier(0);
    __builtin_amdgcn_s_barrier();

    #pragma unroll 2
    for (int t = 0; t < 32; ++t) {
        const int p = t & 1;
        ushort* Ab = lds + (p << 14);
        ushort* Bb = lds + 32768 + (p << 14);
        const int k2 = (t + 2) << 6;
        const bool st = (t < 30);

        FragA fa;                      // reused for m0 then m1
        FragB fb0, fb1;

        // group 1: A-m0 (8 reads) + B-n0 (4 reads) -> quadrant (0,0)
        load_a(fa, Ab, wr * 128, lr, quad);
        load_b(fb0, Bb, wc * 64, lr, quad);
        asm volatile("s_waitcnt lgkmcnt(0)" ::: "memory");
        __builtin_amdgcn_sched_barrier(0);
        __builtin_amdgcn_s_setprio(1);
        mfma_quad(acc, fa, fb0, 0, 0);
        __builtin_amdgcn_s_setprio(0);

        // group 2: B-n1 (4 reads) -> quadrant (0,1)
        load_b(fb1, Bb, wc * 64 + 32, lr, quad);
        asm volatile("s_waitcnt lgkmcnt(0)" ::: "memory");
        __builtin_amdgcn_sched_barrier(0);
        __builtin_amdgcn_s_setprio(1);
        mfma_quad(acc, fa, fb1, 0, 1);
        __builtin_amdgcn_s_setprio(0);

        // group 3: A-m1 (8 reads, reuse fa regs) -> quadrants (1,0),(1,1)
        load_a(fa, Ab, wr * 128 + 64, lr, quad);
        asm volatile("s_waitcnt lgkmcnt(0)" ::: "memory");
        __builtin_amdgcn_sched_barrier(0);
        __builtin_amdgcn_s_setprio(1);
        mfma_quad(acc, fa, fb0, 1, 0);
        mfma_quad(acc, fa, fb1, 1, 1);
        __builtin_amdgcn_s_setprio(0);

        // ---- all reads of buf p done across the block ----
        __builtin_amdgcn_s_barrier();
        if (st) {
            stage64(Ablk, Ab, 0, k2, tid);
            stage64(Ablk, Ab, 1, k2, tid);
            stage64(Ablk, Ab, 2, k2, tid);
            stage64(Ablk, Ab, 3, k2, tid);
            stage64(Bblk, Bb, 0, k2, tid);
            stage64(Bblk, Bb, 1, k2, tid);
            stage64(Bblk, Bb, 2, k2, tid);
            stage64(Bblk, Bb, 3, k2, tid);
            asm volatile("s_waitcnt vmcnt(8)" ::: "memory");   // t+1 resident
        } else {
            asm volatile("s_waitcnt vmcnt(0)" ::: "memory");   // tail drain
        }
        __builtin_amdgcn_sched_barrier(0);
        __builtin_amdgcn_s_barrier();      // t+1 published to all waves
    }
}

// ---------------------------------------------------------------------------
// 2-barrier proj GEMM: out[M][N] f32 = A_bf16 @ Bt_bf16^T. Grid 128 (8Nx16M).
// ---------------------------------------------------------------------------
__global__ __launch_bounds__(512, 2) void gemm_bt_8ph(
    const ushort* __restrict__ A, const ushort* __restrict__ Bt,
    float* __restrict__ Co)
{
    __shared__ __align__(16) ushort lds[65536];    // 128 KiB

    const int tid  = threadIdx.x;
    const int lane = tid & 63;
    const int w    = tid >> 6;
    const int wr   = w >> 2;
    const int wc   = w & 3;
    const int lr   = lane & 15;
    const int quad = lane >> 4;

    // bijective XCD swizzle (nwg=128, 128%8==0)
    int bid = (int)blockIdx.x;
    bid = (bid & 7) * 16 + (bid >> 3);
    const int bx = bid & 7;                // N-tile (8)
    const int by = bid >> 3;               // M-tile (16)

    const ushort* Ablk = A  + (size_t)(by * 256) * C_;
    const ushort* Bblk = Bt + (size_t)(bx * 256) * C_;

    floatx4 acc[8][4];
    #pragma unroll
    for (int i = 0; i < 8; i++)
        #pragma unroll
        for (int j = 0; j < 4; j++)
            acc[i][j] = (floatx4){0.f, 0.f, 0.f, 0.f};

    kloop(Ablk, Bblk, lds, acc, tid);

    const size_t row0 = (size_t)by * 256 + wr * 128;
    const size_t col0 = (size_t)bx * 256 + wc * 64;
    #pragma unroll
    for (int mi = 0; mi < 8; mi++)
        #pragma unroll
        for (int ni = 0; ni < 4; ni++)
            #pragma unroll
            for (int r = 0; r < 4; r++)
                Co[(row0 + mi*16 + quad*4 + r) * (size_t)C_ + col0 + ni*16 + lr]
                    = acc[mi][ni][r];
}

// ---------------------------------------------------------------------------
// 2-barrier fused QKV GEMM. Grid 384 = 24 N-tiles x 16 M-tiles.
//   Per 256-col tile = 2 heads of one of q/k/v.
//   Epilogue (reuses the 128 KiB LDS):
//     q/k: acc -> LDS [t][256] (16B units ^ t&31) -> RoPE -> qb/kb [BH][T][D]
//     v:   acc -> LDS [c][256] transposed (units ^ c&31) -> vt [BH][D][T]
// ---------------------------------------------------------------------------
__global__ __launch_bounds__(512, 2) void gemm_qkv_8ph(
    const ushort* __restrict__ A, const ushort* __restrict__ Bt,
    const float* __restrict__ cosb, const float* __restrict__ sinb,
    ushort* __restrict__ qb, ushort* __restrict__ kbf, ushort* __restrict__ vt)
{
    __shared__ __align__(16) ushort lds[65536];    // 128 KiB

    const int tid  = threadIdx.x;
    const int lane = tid & 63;
    const int w    = tid >> 6;
    const int wr   = w >> 2;
    const int wc   = w & 3;
    const int lr   = lane & 15;
    const int quad = lane >> 4;

    // bijective XCD swizzle (nwg=384, 384%8==0)
    int bid = (int)blockIdx.x;
    bid = (bid & 7) * 48 + (bid >> 3);
    const int bx = bid % 24;               // N-tile
    const int by = bid / 24;               // M-tile

    const ushort* Ablk = A  + (size_t)(by * 256) * C_;
    const ushort* Bblk = Bt + (size_t)(bx * 256) * C_;

    floatx4 acc[8][4];
    #pragma unroll
    for (int i = 0; i < 8; i++)
        #pragma unroll
        for (int j = 0; j < 4; j++)
            acc[i][j] = (floatx4){0.f, 0.f, 0.f, 0.f};

    kloop(Ablk, Bblk, lds, acc, tid);

    // ---- epilogue ----
    const int qt  = bx >> 3;               // 0=q, 1=k, 2=v
    const int h0  = (bx & 7) << 1;         // first of 2 heads in this tile
    const int b   = by >> 3;
    const int t0g = (by & 7) << 8;

    __syncthreads();     // all DMA drained by tail vmcnt(0); reuse LDS

    if (qt < 2) {
        // acc -> LDS [t][256], 16B units XOR-swizzled by (t&31)
        #pragma unroll
        for (int mi = 0; mi < 8; mi++)
            #pragma unroll
            for (int ni = 0; ni < 4; ni++)
                #pragma unroll
                for (int r = 0; r < 4; r++) {
                    const int tt = wr * 128 + mi * 16 + quad * 4 + r;
                    const int cc = wc * 64 + ni * 16 + lr;
                    lds[tt * 256 + ((((cc >> 3) ^ (tt & 31)) << 3) | (cc & 7))]
                        = f2bf(acc[mi][ni][r]);
                }
        __syncthreads();

        // thread -> row t = tid>>1, head-half hsel = tid&1
        const int trow = tid >> 1;
        const int hsel = tid & 1;
        const int tg   = t0g + trow;
        const int bh   = b * 16 + h0 + hsel;
        ushort* outp = (qt == 0 ? qb : kbf) + ((size_t)bh * T_ + tg) * D_;
        const float4* cp4 = (const float4*)(cosb + (size_t)tg * 64);
        const float4* sp4 = (const float4*)(sinb + (size_t)tg * 64);
        const ushort* rowp = lds + trow * 256;
        const int tw = trow & 31;
        #pragma unroll
        for (int u = 0; u < 8; u++) {
            bf16x8 x1 = *(const bf16x8*)(rowp + (((hsel * 16 + u)     ^ tw) << 3));
            bf16x8 x2 = *(const bf16x8*)(rowp + (((hsel * 16 + 8 + u) ^ tw) << 3));
            float cc[8], ss[8];
            *(float4*)(cc)     = cp4[u * 2];
            *(float4*)(cc + 4) = cp4[u * 2 + 1];
            *(float4*)(ss)     = sp4[u * 2];
            *(float4*)(ss + 4) = sp4[u * 2 + 1];
            ushortx8 lo, hi;
            #pragma unroll
            for (int e = 0; e < 8; e++) {
                const float x1f = (float)x1[e];
                const float x2f = (float)x2[e];
                lo[e] = f2bf(x1f * cc[e] - x2f * ss[e]);
                hi[e] = f2bf(x1f * ss[e] + x2f * cc[e]);
            }
            *(ushortx8*)(outp + u * 8)      = lo;
            *(ushortx8*)(outp + 64 + u * 8) = hi;
        }
    } else {
        // v: acc -> LDS [c][256] (t-major within row), units swizzled by c&31
        #pragma unroll
        for (int mi = 0; mi < 8; mi++)
            #pragma unroll
            for (int ni = 0; ni < 4; ni++)
                #pragma unroll
                for (int r = 0; r < 4; r++) {
                    const int tt = wr * 128 + mi * 16 + quad * 4 + r;
                    const int cc = wc * 64 + ni * 16 + lr;
                    lds[cc * 256 + ((((tt >> 3) ^ (cc & 31)) << 3) | (tt & 7))]
                        = f2bf(acc[mi][ni][r]);
                }
        __syncthreads();

        const int c  = tid >> 1;           // local column 0..255
        const int hT = tid & 1;            // t-half (128 each)
        const int hh = c >> 7;             // head within tile
        const int d  = c & 127;
        const int bh = b * 16 + h0 + hh;
        const ushort* rowp = lds + c * 256;
        const int cw = c & 31;
        ushort* outp = vt + ((size_t)bh * D_ + d) * T_ + t0g + hT * 128;
        #pragma unroll
        for (int u = 0; u < 16; u++) {
            bf16x8 vv = *(const bf16x8*)(rowp + (((hT * 16 + u) ^ cw) << 3));
            *(bf16x8*)(outp + u * 8) = vv;
        }
    }
}

// ---------------------------------------------------------------------------
// Cooperative causal flash attention, static-shift softmax.
// Output bf16 [M][C] so the proj GEMM consumes it directly.
// ---------------------------------------------------------------------------
__global__ __launch_bounds__(256, 4) void flash_attn(
    const ushort* __restrict__ qb, const ushort* __restrict__ kb,
    const ushort* __restrict__ vt, ushort* __restrict__ attnoutb)
{
    __shared__ __align__(16) ushort kt_s[64 * 128];      // [key][d], units ^key
    __shared__ __align__(16) ushort vt_s[128 * 64];      // [d][key], units ^d
    __shared__ __align__(16) ushort pl_s[4][16 * 40];    // per-wave P tile

    const int w    = threadIdx.x >> 6;
    const int lane = threadIdx.x & 63;
    const int lr   = lane & 15;
    const int quad = lane >> 4;

    const int bh = blockIdx.x & 31;
    const int m  = 31 - (blockIdx.x >> 5);    // longest key-ranges first
    const int qt = 4 * m + w;
    const int qbase = qt * 16;
    const int nk = m + 1;
    const int bb = bh >> 4, hh = bh & 15;

    const ushort* kbp = kb + (size_t)bh * T_ * D_;
    const ushort* vbp = vt + (size_t)bh * D_ * T_;
    ushort* pl = pl_s[w];

    bf16x8 qf[4];
    const ushort* qrow = qb + ((size_t)bh * T_ + qbase + lr) * D_ + quad * 8;
    #pragma unroll
    for (int kc = 0; kc < 4; kc++)
        qf[kc] = *(const bf16x8*)(qrow + kc * 32);

    floatx4 o[8];
    #pragma unroll
    for (int dc = 0; dc < 8; dc++) o[dc] = (floatx4){0.f, 0.f, 0.f, 0.f};
    floatx4 lac = (floatx4){0.f, 0.f, 0.f, 0.f};

    const __bf16 one = (__bf16)1.0f;
    const bf16x8 ones = {one, one, one, one, one, one, one, one};
    const float SCL  = 0.08838834764831845f * 1.4426950408889634f;
    const float BIAS = 23.083120654223414f;

    const int krow4 = lane >> 4;
    const int kunit = lane & 15;
    const int vrow8 = lane >> 3;
    const int vunit = lane & 7;

    for (int kt = 0; kt < nk; ++kt) {
        const int kb0 = kt * 64;
        __syncthreads();
        #pragma unroll
        for (int j = 0; j < 4; j++) {
            const int row = w * 16 + j * 4 + krow4;
            const ushort* gp = kbp + (size_t)(kb0 + row) * D_
                                   + ((kunit ^ (row & 15)) << 3);
            async16(gp, kt_s + (w * 16 + j * 4) * 128);
        }
        #pragma unroll
        for (int j = 0; j < 4; j++) {
            const int row = w * 32 + j * 8 + vrow8;
            const ushort* gp = vbp + (size_t)row * T_ + kb0
                                   + ((vunit ^ (row & 7)) << 3);
            async16(gp, vt_s + (w * 32 + j * 8) * 64);
        }
        __syncthreads();

        #pragma unroll
        for (int half = 0; half < 2; ++half) {
            floatx4 st[2];
            #pragma unroll
            for (int jj = 0; jj < 2; ++jj) {
                const int j = half * 2 + jj;
                floatx4 s = (floatx4){0.f, 0.f, 0.f, 0.f};
                const int kl = j * 16 + lr;
                #pragma unroll
                for (int kc = 0; kc < 4; kc++) {
                    bf16x8 af = *(const bf16x8*)(
                        kt_s + kl * 128 + ((((kc << 2) | quad) ^ lr) << 3));
                    s = mfma_bf16(af, qf[kc], s);
                }
                st[jj] = s;
            }
            #pragma unroll
            for (int jj = 0; jj < 2; ++jj) {
                const int j = half * 2 + jj;
                const int kg0 = kb0 + j * 16 + quad * 4;
                float p[4];
                #pragma unroll
                for (int r = 0; r < 4; r++) {
                    float e = __builtin_amdgcn_exp2f(fmaf(st[jj][r], SCL, -BIAS));
                    p[r] = (kg0 + r > qbase + lr) ? 0.f : e;
                }
                uint2 pk;
                pk.x = (uint32_t)f2bf(p[0]) | ((uint32_t)f2bf(p[1]) << 16);
                pk.y = (uint32_t)f2bf(p[2]) | ((uint32_t)f2bf(p[3]) << 16);
                *(uint2*)(pl + lr * 40 + jj * 16 + quad * 4) = pk;
            }
            bf16x8 pf = *(const bf16x8*)(pl + lr * 40 + quad * 8);
            lac = mfma_bf16(pf, ones, lac);
            #pragma unroll
            for (int dc = 0; dc < 8; dc++) {
                const int d = dc * 16 + lr;
                bf16x8 vf = *(const bf16x8*)(
                    vt_s + d * 64 + ((((half << 2) | quad) ^ (lr & 7)) << 3));
                o[dc] = mfma_bf16(pf, vf, o[dc]);
            }
        }
    }

    #pragma unroll
    for (int dc = 0; dc < 8; dc++)
        #pragma unroll
        for (int r = 0; r < 4; r++) {
            const int trow = qbase + quad * 4 + r;
            attnoutb[((size_t)(bb * T_ + trow)) * C_ + hh * D_ + dc * 16 + lr]
                = f2bf(o[dc][r] / lac[r]);
        }
}

// ---------------------------------------------------------------------------
extern "C" void kernel_launch(void* const* d_in, const int* in_sizes, int n_in,
                              void* d_out, int out_size, void* d_ws, size_t ws_size,
                              hipStream_t stream)
{
    (void)in_sizes; (void)n_in; (void)out_size; (void)ws_size;
    const float* x     = (const float*)d_in[0];
    const float* cosb  = (const float*)d_in[1];
    const float* sinb  = (const float*)d_in[2];
    const float* Wqkv  = (const float*)d_in[3];
    const float* Wproj = (const float*)d_in[4];
    float* out = (float*)d_out;

    // Workspace (117,440,512 B used):
    //  xb   [M][C] bf16        @ 0          (16,777,216)
    //  Wtq  [3C][C] bf16       @ 16777216   (25,165,824)
    //  Wtp  [C][C] bf16        @ 41943040   ( 8,388,608)
    //  qb   [BH][T][D] bf16    @ 50331648   (16,777,216)
    //  kb   [BH][T][D] bf16    @ 67108864   (16,777,216)
    //  vt   [BH][D][T] bf16    @ 83886080   (16,777,216)
    //  attn [M][C] bf16        @ 100663296  (16,777,216)
    char* ws = (char*)d_ws;
    ushort* xb       = (ushort*)(ws);
    ushort* Wtq      = (ushort*)(ws + 16777216);
    ushort* Wtp      = (ushort*)(ws + 41943040);
    ushort* qb       = (ushort*)(ws + 50331648);
    ushort* kbf      = (ushort*)(ws + 67108864);
    ushort* vt       = (ushort*)(ws + 83886080);
    ushort* attnoutb = (ushort*)(ws + 100663296);

    dim3 tb32(32, 8);
    transpose_w<<<dim3(3 * C_ / 32, C_ / 32), tb32, 0, stream>>>(Wqkv, Wtq, C_, 3 * C_);
    transpose_w<<<dim3(C_ / 32, C_ / 32),     tb32, 0, stream>>>(Wproj, Wtp, C_, C_);
    convert_bf16<<<(M_ * C_ / 4) / 256, 256, 0, stream>>>(x, xb);

    gemm_qkv_8ph<<<384, 512, 0, stream>>>(xb, Wtq, cosb, sinb, qb, kbf, vt);

    flash_attn<<<BH_ * 32, 256, 0, stream>>>(qb, kbf, vt, attnoutb);

    gemm_bt_8ph<<<128, 512, 0, stream>>>(attnoutb, Wtp, out);
}

// Round 5
// 411.635 us; speedup vs baseline: 1.0122x; 1.0122x over previous
//
#include <hip/hip_runtime.h>
#include <stdint.h>

// Problem constants
#define B_  2
#define T_  2048
#define C_  2048
#define H_  16
#define D_  128
#define BH_ 32        // B*H
#define M_  4096      // B*T

typedef __attribute__((ext_vector_type(8))) __bf16  bf16x8;
typedef __attribute__((ext_vector_type(4))) float   floatx4;
typedef __attribute__((ext_vector_type(4))) ushort  ushortx4;

__device__ __forceinline__ ushort f2bf(float f) {
    union { float f; uint32_t u; } v; v.f = f;
    return (ushort)((v.u + 0x7fffu + ((v.u >> 16) & 1u)) >> 16);
}

__device__ __forceinline__ float bf2f(ushort u) {
    union { uint32_t u; float f; } v; v.u = ((uint32_t)u) << 16;
    return v.f;
}

__device__ __forceinline__ floatx4 mfma_bf16(bf16x8 a, bf16x8 b, floatx4 c) {
    return __builtin_amdgcn_mfma_f32_16x16x32_bf16(a, b, c, 0, 0, 0);
}

// async global->LDS, 16B per lane; lds dest = wave-uniform base + lane*16
__device__ __forceinline__ void async16(const ushort* g, ushort* l) {
    __builtin_amdgcn_global_load_lds(
        (const __attribute__((address_space(1))) uint32_t*)g,
        (__attribute__((address_space(3))) uint32_t*)l, 16, 0, 0);
}

// ---------------------------------------------------------------------------
// x f32 -> bf16 (vectorized 4-wide)
// ---------------------------------------------------------------------------
__global__ __launch_bounds__(256) void convert_bf16(
    const float* __restrict__ X, ushort* __restrict__ Xb)
{
    const int i = blockIdx.x * 256 + threadIdx.x;
    const float4 v = ((const float4*)X)[i];
    ushortx4 p = { f2bf(v.x), f2bf(v.y), f2bf(v.z), f2bf(v.w) };
    ((ushortx4*)Xb)[i] = p;
}

// ---------------------------------------------------------------------------
// Transpose + convert: W f32 [K][N] -> Wt bf16 [N][K]
// ---------------------------------------------------------------------------
__global__ __launch_bounds__(256) void transpose_w(
    const float* __restrict__ W, ushort* __restrict__ Wt, int Kdim, int Ndim)
{
    __shared__ float tile[32][33];
    const int n0 = blockIdx.x * 32, k0 = blockIdx.y * 32;
    const int tx = threadIdx.x, ty = threadIdx.y;
    #pragma unroll
    for (int j = 0; j < 4; j++)
        tile[ty + j*8][tx] = W[(size_t)(k0 + ty + j*8) * Ndim + n0 + tx];
    __syncthreads();
    #pragma unroll
    for (int j = 0; j < 4; j++)
        Wt[(size_t)(n0 + ty + j*8) * Kdim + k0 + tx] = f2bf(tile[tx][ty + j*8]);
}

// ---------------------------------------------------------------------------
// Plain GEMM (m97 structure): C[M][N] = A_bf16 @ Bt_bf16^T, C f32. (proj)
// Grid (16, 32) = 512 blocks; bijective XCD swizzle (512 % 8 == 0) groups
// 4 contiguous by-rows per XCD -> A panels L2-resident, B panels x4 reuse.
// ---------------------------------------------------------------------------
#define BM 128
#define BN 128
#define BK 32

__global__ __launch_bounds__(256) void gemm_bt(
    const ushort* __restrict__ A, const ushort* __restrict__ Bt,
    float* __restrict__ Co, int Ndim, int Kdim)
{
    __shared__ __align__(16) ushort As[BM * BK];
    __shared__ __align__(16) ushort Bs[BN * BK];
    const int tid  = threadIdx.x;
    const int lane = tid & 63;
    const int w    = tid >> 6;
    const int wm   = (w >> 1) * 64;
    const int wn   = (w & 1) * 64;
    const int lr   = lane & 15;
    const int quad = lane >> 4;
    const int srow = lane >> 2;
    const int soff = (lane & 3) * 8;

    // XCD swizzle: grid (16,32), lid = by*16+bx, 512 blocks, 512%8==0
    const int lid = (int)blockIdx.y * 16 + (int)blockIdx.x;
    const int nid = (lid & 7) * 64 + (lid >> 3);
    const int bx  = nid & 15;
    const int by  = nid >> 4;

    const ushort* Ablk = A  + (size_t)(by * BM) * Kdim;
    const ushort* Bblk = Bt + (size_t)(bx * BN) * Kdim;

    floatx4 acc[4][4];
    #pragma unroll
    for (int i = 0; i < 4; i++)
        #pragma unroll
        for (int j = 0; j < 4; j++)
            acc[i][j] = (floatx4){0.f, 0.f, 0.f, 0.f};

    for (int k0 = 0; k0 < Kdim; k0 += BK) {
        __syncthreads();
        #pragma unroll
        for (int j = 0; j < 2; j++) {
            const int row = w * 32 + j * 16 + srow;
            async16(Ablk + (size_t)row * Kdim + k0 + soff,
                    As + (w * 32 + j * 16) * BK);
            async16(Bblk + (size_t)row * Kdim + k0 + soff,
                    Bs + (w * 32 + j * 16) * BK);
        }
        __syncthreads();

        bf16x8 af[4], bfr[4];
        #pragma unroll
        for (int mi = 0; mi < 4; mi++)
            af[mi] = *(const bf16x8*)(&As[(wm + mi*16 + lr) * BK + quad * 8]);
        #pragma unroll
        for (int ni = 0; ni < 4; ni++)
            bfr[ni] = *(const bf16x8*)(&Bs[(wn + ni*16 + lr) * BK + quad * 8]);
        #pragma unroll
        for (int mi = 0; mi < 4; mi++)
            #pragma unroll
            for (int ni = 0; ni < 4; ni++)
                acc[mi][ni] = mfma_bf16(af[mi], bfr[ni], acc[mi][ni]);
    }

    const size_t row0 = (size_t)by * BM + wm;
    const size_t col0 = (size_t)bx * BN + wn;
    #pragma unroll
    for (int mi = 0; mi < 4; mi++)
        #pragma unroll
        for (int ni = 0; ni < 4; ni++)
            #pragma unroll
            for (int r = 0; r < 4; r++)
                Co[(row0 + mi*16 + quad*4 + r) * (size_t)Ndim + col0 + ni*16 + lr]
                    = acc[mi][ni][r];
}

// ---------------------------------------------------------------------------
// Fused QKV GEMM: same K-loop; epilogue produces flash-ready tensors.
// Grid (48, 32) = 1536 blocks (6/CU, balanced); bijective XCD swizzle
// (1536 % 8 == 0): each XCD owns 4 contiguous by-rows x all bx -> A panels
// (4 x 512 KB) stay in the XCD's 4 MB L2, B panels get 4x concurrent reuse.
// bx -> qt = bx>>4 (0=q,1=k,2=v), head h = bx&15; by -> b = by>>4,
// t0 = (by&15)*128. Each block owns one head's 128x128 (t x d) tile.
//   q/k: acc -> LDS [t][136] bf16 -> pair-closed readback -> RoPE -> qb/kb
//        [BH][T][D] bf16, b128 stores.
//   v:   acc -> LDS [d][128] with 8-elem units XOR-swizzled by (d&15)
//        -> contiguous-t readback -> vt [BH][D][T] bf16, b128 stores.
// ---------------------------------------------------------------------------
__global__ __launch_bounds__(256) void gemm_qkv(
    const ushort* __restrict__ A, const ushort* __restrict__ Bt,
    const float* __restrict__ cosb, const float* __restrict__ sinb,
    ushort* __restrict__ qb, ushort* __restrict__ kbf, ushort* __restrict__ vt)
{
    __shared__ __align__(16) ushort smem[17408];   // 34,816 B
    ushort* As = smem;          // 128*32
    ushort* Bs = smem + 4096;   // 128*32

    const int tid  = threadIdx.x;
    const int lane = tid & 63;
    const int w    = tid >> 6;
    const int wm   = (w >> 1) * 64;
    const int wn   = (w & 1) * 64;
    const int lr   = lane & 15;
    const int quad = lane >> 4;
    const int srow = lane >> 2;
    const int soff = (lane & 3) * 8;

    // XCD swizzle: grid (48,32), lid = by*48+bx, 1536 blocks, 1536%8==0
    const int lid = (int)blockIdx.y * 48 + (int)blockIdx.x;
    const int nid = (lid & 7) * 192 + (lid >> 3);
    const int bx  = nid % 48;
    const int by  = nid / 48;

    const int Kdim = C_;
    const ushort* Ablk = A  + (size_t)(by * BM) * Kdim;
    const ushort* Bblk = Bt + (size_t)(bx * BN) * Kdim;

    floatx4 acc[4][4];
    #pragma unroll
    for (int i = 0; i < 4; i++)
        #pragma unroll
        for (int j = 0; j < 4; j++)
            acc[i][j] = (floatx4){0.f, 0.f, 0.f, 0.f};

    for (int k0 = 0; k0 < Kdim; k0 += BK) {
        __syncthreads();
        #pragma unroll
        for (int j = 0; j < 2; j++) {
            const int row = w * 32 + j * 16 + srow;
            async16(Ablk + (size_t)row * Kdim + k0 + soff,
                    As + (w * 32 + j * 16) * BK);
            async16(Bblk + (size_t)row * Kdim + k0 + soff,
                    Bs + (w * 32 + j * 16) * BK);
        }
        __syncthreads();

        bf16x8 af[4], bfr[4];
        #pragma unroll
        for (int mi = 0; mi < 4; mi++)
            af[mi] = *(const bf16x8*)(&As[(wm + mi*16 + lr) * BK + quad * 8]);
        #pragma unroll
        for (int ni = 0; ni < 4; ni++)
            bfr[ni] = *(const bf16x8*)(&Bs[(wn + ni*16 + lr) * BK + quad * 8]);
        #pragma unroll
        for (int mi = 0; mi < 4; mi++)
            #pragma unroll
            for (int ni = 0; ni < 4; ni++)
                acc[mi][ni] = mfma_bf16(af[mi], bfr[ni], acc[mi][ni]);
    }

    // ---- epilogue ----
    const int h   = bx & 15;
    const int qt  = bx >> 4;
    const int b   = by >> 4;
    const int t0g = (by & 15) * 128;
    const int bh  = b * 16 + h;

    __syncthreads();   // all frag reads done before smem reuse

    if (qt < 2) {
        // acc -> LDS [t][136] bf16
        #pragma unroll
        for (int mi = 0; mi < 4; mi++)
            #pragma unroll
            for (int ni = 0; ni < 4; ni++)
                #pragma unroll
                for (int r = 0; r < 4; r++) {
                    const int t = wm + mi*16 + quad*4 + r;
                    const int d = wn + ni*16 + lr;
                    smem[t * 136 + d] = f2bf(acc[mi][ni][r]);
                }
        __syncthreads();

        // readback: thread -> row t = tid>>1, d-chunks [c0,c0+32) and +64
        const int t  = tid >> 1;
        const int c0 = (tid & 1) * 32;
        bf16x8 x1v[4], x2v[4];
        #pragma unroll
        for (int u = 0; u < 4; u++) {
            x1v[u] = *(const bf16x8*)(smem + t * 136 + c0 + u * 8);
            x2v[u] = *(const bf16x8*)(smem + t * 136 + 64 + c0 + u * 8);
        }
        const float4* cp4 = (const float4*)(cosb + (size_t)(t0g + t) * 64 + c0);
        const float4* sp4 = (const float4*)(sinb + (size_t)(t0g + t) * 64 + c0);
        ushort* outp = (qt == 0 ? qb : kbf) + ((size_t)bh * T_ + t0g + t) * D_;
        #pragma unroll
        for (int u = 0; u < 4; u++) {
            float cc[8], ss[8];
            *(float4*)(cc)     = cp4[u * 2];
            *(float4*)(cc + 4) = cp4[u * 2 + 1];
            *(float4*)(ss)     = sp4[u * 2];
            *(float4*)(ss + 4) = sp4[u * 2 + 1];
            ushortx4 lo0, lo1, hi0, hi1;
            #pragma unroll
            for (int e = 0; e < 8; e++) {
                const float x1 = (float)x1v[u][e];
                const float x2 = (float)x2v[u][e];
                const ushort vlo = f2bf(x1 * cc[e] - x2 * ss[e]);
                const ushort vhi = f2bf(x1 * ss[e] + x2 * cc[e]);
                if (e < 4) { lo0[e] = vlo; hi0[e] = vhi; }
                else       { lo1[e-4] = vlo; hi1[e-4] = vhi; }
            }
            *(ushortx4*)(outp + c0 + u*8)          = lo0;
            *(ushortx4*)(outp + c0 + u*8 + 4)      = lo1;
            *(ushortx4*)(outp + 64 + c0 + u*8)     = hi0;
            *(ushortx4*)(outp + 64 + c0 + u*8 + 4) = hi1;
        }
    } else {
        // v: acc -> LDS transposed [d][128], units swizzled by d
        #pragma unroll
        for (int mi = 0; mi < 4; mi++)
            #pragma unroll
            for (int ni = 0; ni < 4; ni++)
                #pragma unroll
                for (int r = 0; r < 4; r++) {
                    const int t = wm + mi*16 + quad*4 + r;
                    const int d = wn + ni*16 + lr;
                    smem[d * 128 + (t & 7) + 8 * ((t >> 3) ^ (d & 15))]
                        = f2bf(acc[mi][ni][r]);
                }
        __syncthreads();

        const int d    = tid >> 1;
        const int half = tid & 1;
        ushort* outp = vt + ((size_t)bh * D_ + d) * T_ + t0g + half * 64;
        #pragma unroll
        for (int u = 0; u < 8; u++) {
            const int gu = half * 8 + u;
            bf16x8 vv = *(const bf16x8*)(smem + d * 128 + 8 * (gu ^ (d & 15)));
            *(bf16x8*)(outp + u * 8) = vv;
        }
    }
}

// ---------------------------------------------------------------------------
// Cooperative causal flash attention, static-shift softmax.
// Output bf16 [M][C] so the proj GEMM consumes it directly.
// ---------------------------------------------------------------------------
__global__ __launch_bounds__(256, 4) void flash_attn(
    const ushort* __restrict__ qb, const ushort* __restrict__ kb,
    const ushort* __restrict__ vt, ushort* __restrict__ attnoutb)
{
    __shared__ __align__(16) ushort kt_s[64 * 128];      // [key][d], units ^key
    __shared__ __align__(16) ushort vt_s[128 * 64];      // [d][key], units ^d
    __shared__ __align__(16) ushort pl_s[4][16 * 40];    // per-wave P tile

    const int w    = threadIdx.x >> 6;
    const int lane = threadIdx.x & 63;
    const int lr   = lane & 15;
    const int quad = lane >> 4;

    const int bh = blockIdx.x & 31;
    const int m  = 31 - (blockIdx.x >> 5);    // longest key-ranges first
    const int qt = 4 * m + w;
    const int qbase = qt * 16;
    const int nk = m + 1;
    const int bb = bh >> 4, hh = bh & 15;

    const ushort* kbp = kb + (size_t)bh * T_ * D_;
    const ushort* vbp = vt + (size_t)bh * D_ * T_;
    ushort* pl = pl_s[w];

    bf16x8 qf[4];
    const ushort* qrow = qb + ((size_t)bh * T_ + qbase + lr) * D_ + quad * 8;
    #pragma unroll
    for (int kc = 0; kc < 4; kc++)
        qf[kc] = *(const bf16x8*)(qrow + kc * 32);

    floatx4 o[8];
    #pragma unroll
    for (int dc = 0; dc < 8; dc++) o[dc] = (floatx4){0.f, 0.f, 0.f, 0.f};
    floatx4 lac = (floatx4){0.f, 0.f, 0.f, 0.f};

    const __bf16 one = (__bf16)1.0f;
    const bf16x8 ones = {one, one, one, one, one, one, one, one};
    const float SCL  = 0.08838834764831845f * 1.4426950408889634f;
    const float BIAS = 23.083120654223414f;

    const int krow4 = lane >> 4;
    const int kunit = lane & 15;
    const int vrow8 = lane >> 3;
    const int vunit = lane & 7;

    for (int kt = 0; kt < nk; ++kt) {
        const int kb0 = kt * 64;
        __syncthreads();
        #pragma unroll
        for (int j = 0; j < 4; j++) {
            const int row = w * 16 + j * 4 + krow4;
            const ushort* gp = kbp + (size_t)(kb0 + row) * D_
                                   + ((kunit ^ (row & 15)) << 3);
            async16(gp, kt_s + (w * 16 + j * 4) * 128);
        }
        #pragma unroll
        for (int j = 0; j < 4; j++) {
            const int row = w * 32 + j * 8 + vrow8;
            const ushort* gp = vbp + (size_t)row * T_ + kb0
                                   + ((vunit ^ (row & 7)) << 3);
            async16(gp, vt_s + (w * 32 + j * 8) * 64);
        }
        __syncthreads();

        #pragma unroll
        for (int half = 0; half < 2; ++half) {
            floatx4 st[2];
            #pragma unroll
            for (int jj = 0; jj < 2; ++jj) {
                const int j = half * 2 + jj;
                floatx4 s = (floatx4){0.f, 0.f, 0.f, 0.f};
                const int kl = j * 16 + lr;
                #pragma unroll
                for (int kc = 0; kc < 4; kc++) {
                    bf16x8 af = *(const bf16x8*)(
                        kt_s + kl * 128 + ((((kc << 2) | quad) ^ lr) << 3));
                    s = mfma_bf16(af, qf[kc], s);
                }
                st[jj] = s;
            }
            #pragma unroll
            for (int jj = 0; jj < 2; ++jj) {
                const int j = half * 2 + jj;
                const int kg0 = kb0 + j * 16 + quad * 4;
                float p[4];
                #pragma unroll
                for (int r = 0; r < 4; r++) {
                    float e = __builtin_amdgcn_exp2f(fmaf(st[jj][r], SCL, -BIAS));
                    p[r] = (kg0 + r > qbase + lr) ? 0.f : e;
                }
                uint2 pk;
                pk.x = (uint32_t)f2bf(p[0]) | ((uint32_t)f2bf(p[1]) << 16);
                pk.y = (uint32_t)f2bf(p[2]) | ((uint32_t)f2bf(p[3]) << 16);
                *(uint2*)(pl + lr * 40 + jj * 16 + quad * 4) = pk;
            }
            bf16x8 pf = *(const bf16x8*)(pl + lr * 40 + quad * 8);
            lac = mfma_bf16(pf, ones, lac);
            #pragma unroll
            for (int dc = 0; dc < 8; dc++) {
                const int d = dc * 16 + lr;
                bf16x8 vf = *(const bf16x8*)(
                    vt_s + d * 64 + ((((half << 2) | quad) ^ (lr & 7)) << 3));
                o[dc] = mfma_bf16(pf, vf, o[dc]);
            }
        }
    }

    #pragma unroll
    for (int dc = 0; dc < 8; dc++)
        #pragma unroll
        for (int r = 0; r < 4; r++) {
            const int trow = qbase + quad * 4 + r;
            attnoutb[((size_t)(bb * T_ + trow)) * C_ + hh * D_ + dc * 16 + lr]
                = f2bf(o[dc][r] / lac[r]);
        }
}

// ---------------------------------------------------------------------------
extern "C" void kernel_launch(void* const* d_in, const int* in_sizes, int n_in,
                              void* d_out, int out_size, void* d_ws, size_t ws_size,
                              hipStream_t stream)
{
    (void)in_sizes; (void)n_in; (void)out_size; (void)ws_size;
    const float* x     = (const float*)d_in[0];
    const float* cosb  = (const float*)d_in[1];
    const float* sinb  = (const float*)d_in[2];
    const float* Wqkv  = (const float*)d_in[3];
    const float* Wproj = (const float*)d_in[4];
    float* out = (float*)d_out;

    // Workspace (117,440,512 B used):
    //  xb   [M][C] bf16        @ 0          (16,777,216)
    //  Wtq  [3C][C] bf16       @ 16777216   (25,165,824)
    //  Wtp  [C][C] bf16        @ 41943040   ( 8,388,608)
    //  qb   [BH][T][D] bf16    @ 50331648   (16,777,216)
    //  kb   [BH][T][D] bf16    @ 67108864   (16,777,216)
    //  vt   [BH][D][T] bf16    @ 83886080   (16,777,216)
    //  attn [M][C] bf16        @ 100663296  (16,777,216)
    char* ws = (char*)d_ws;
    ushort* xb       = (ushort*)(ws);
    ushort* Wtq      = (ushort*)(ws + 16777216);
    ushort* Wtp      = (ushort*)(ws + 41943040);
    ushort* qb       = (ushort*)(ws + 50331648);
    ushort* kbf      = (ushort*)(ws + 67108864);
    ushort* vt       = (ushort*)(ws + 83886080);
    ushort* attnoutb = (ushort*)(ws + 100663296);

    dim3 tb32(32, 8);
    transpose_w<<<dim3(3 * C_ / 32, C_ / 32), tb32, 0, stream>>>(Wqkv, Wtq, C_, 3 * C_);
    transpose_w<<<dim3(C_ / 32, C_ / 32),     tb32, 0, stream>>>(Wproj, Wtp, C_, C_);
    convert_bf16<<<(M_ * C_ / 4) / 256, 256, 0, stream>>>(x, xb);

    gemm_qkv<<<dim3(3 * C_ / BN, M_ / BM), 256, 0, stream>>>(
        xb, Wtq, cosb, sinb, qb, kbf, vt);

    flash_attn<<<BH_ * 32, 256, 0, stream>>>(qb, kbf, vt, attnoutb);

    gemm_bt<<<dim3(C_ / BN, M_ / BM), 256, 0, stream>>>(attnoutb, Wtp, out, C_, C_);
}

// Round 6
// 406.356 us; speedup vs baseline: 1.0253x; 1.0130x over previous
//
#include <hip/hip_runtime.h>
#include <stdint.h>

// Problem constants
#define B_  2
#define T_  2048
#define C_  2048
#define H_  16
#define D_  128
#define BH_ 32        // B*H
#define M_  4096      // B*T

typedef __attribute__((ext_vector_type(8))) __bf16  bf16x8;
typedef __attribute__((ext_vector_type(4))) float   floatx4;
typedef __attribute__((ext_vector_type(4))) ushort  ushortx4;

__device__ __forceinline__ ushort f2bf(float f) {
    union { float f; uint32_t u; } v; v.f = f;
    return (ushort)((v.u + 0x7fffu + ((v.u >> 16) & 1u)) >> 16);
}

__device__ __forceinline__ float bf2f(ushort u) {
    union { uint32_t u; float f; } v; v.u = ((uint32_t)u) << 16;
    return v.f;
}

__device__ __forceinline__ floatx4 mfma_bf16(bf16x8 a, bf16x8 b, floatx4 c) {
    return __builtin_amdgcn_mfma_f32_16x16x32_bf16(a, b, c, 0, 0, 0);
}

// async global->LDS, 16B per lane; lds dest = wave-uniform base + lane*16
__device__ __forceinline__ void async16(const ushort* g, ushort* l) {
    __builtin_amdgcn_global_load_lds(
        (const __attribute__((address_space(1))) uint32_t*)g,
        (__attribute__((address_space(3))) uint32_t*)l, 16, 0, 0);
}

// ---------------------------------------------------------------------------
// x f32 -> bf16 (vectorized 4-wide)
// ---------------------------------------------------------------------------
__global__ __launch_bounds__(256) void convert_bf16(
    const float* __restrict__ X, ushort* __restrict__ Xb)
{
    const int i = blockIdx.x * 256 + threadIdx.x;
    const float4 v = ((const float4*)X)[i];
    ushortx4 p = { f2bf(v.x), f2bf(v.y), f2bf(v.z), f2bf(v.w) };
    ((ushortx4*)Xb)[i] = p;
}

// ---------------------------------------------------------------------------
// Transpose + convert: W f32 [K][N] -> Wt bf16 [N][K]
// ---------------------------------------------------------------------------
__global__ __launch_bounds__(256) void transpose_w(
    const float* __restrict__ W, ushort* __restrict__ Wt, int Kdim, int Ndim)
{
    __shared__ float tile[32][33];
    const int n0 = blockIdx.x * 32, k0 = blockIdx.y * 32;
    const int tx = threadIdx.x, ty = threadIdx.y;
    #pragma unroll
    for (int j = 0; j < 4; j++)
        tile[ty + j*8][tx] = W[(size_t)(k0 + ty + j*8) * Ndim + n0 + tx];
    __syncthreads();
    #pragma unroll
    for (int j = 0; j < 4; j++)
        Wt[(size_t)(n0 + ty + j*8) * Kdim + k0 + tx] = f2bf(tile[tx][ty + j*8]);
}

// ---------------------------------------------------------------------------
// Plain GEMM (m97 structure): C[M][N] = A_bf16 @ Bt_bf16^T, C f32. (proj)
// (exact R0 version; R5 showed XCD swizzle raises FETCH 2.7x with no gain)
// ---------------------------------------------------------------------------
#define BM 128
#define BN 128
#define BK 32

__global__ __launch_bounds__(256) void gemm_bt(
    const ushort* __restrict__ A, const ushort* __restrict__ Bt,
    float* __restrict__ Co, int Ndim, int Kdim)
{
    __shared__ __align__(16) ushort As[BM * BK];
    __shared__ __align__(16) ushort Bs[BN * BK];
    const int tid  = threadIdx.x;
    const int lane = tid & 63;
    const int w    = tid >> 6;
    const int wm   = (w >> 1) * 64;
    const int wn   = (w & 1) * 64;
    const int lr   = lane & 15;
    const int quad = lane >> 4;
    const int srow = lane >> 2;
    const int soff = (lane & 3) * 8;

    const ushort* Ablk = A  + (size_t)(blockIdx.y * BM) * Kdim;
    const ushort* Bblk = Bt + (size_t)(blockIdx.x * BN) * Kdim;

    floatx4 acc[4][4];
    #pragma unroll
    for (int i = 0; i < 4; i++)
        #pragma unroll
        for (int j = 0; j < 4; j++)
            acc[i][j] = (floatx4){0.f, 0.f, 0.f, 0.f};

    for (int k0 = 0; k0 < Kdim; k0 += BK) {
        __syncthreads();
        #pragma unroll
        for (int j = 0; j < 2; j++) {
            const int row = w * 32 + j * 16 + srow;
            async16(Ablk + (size_t)row * Kdim + k0 + soff,
                    As + (w * 32 + j * 16) * BK);
            async16(Bblk + (size_t)row * Kdim + k0 + soff,
                    Bs + (w * 32 + j * 16) * BK);
        }
        __syncthreads();

        bf16x8 af[4], bfr[4];
        #pragma unroll
        for (int mi = 0; mi < 4; mi++)
            af[mi] = *(const bf16x8*)(&As[(wm + mi*16 + lr) * BK + quad * 8]);
        #pragma unroll
        for (int ni = 0; ni < 4; ni++)
            bfr[ni] = *(const bf16x8*)(&Bs[(wn + ni*16 + lr) * BK + quad * 8]);
        #pragma unroll
        for (int mi = 0; mi < 4; mi++)
            #pragma unroll
            for (int ni = 0; ni < 4; ni++)
                acc[mi][ni] = mfma_bf16(af[mi], bfr[ni], acc[mi][ni]);
    }

    const size_t row0 = (size_t)blockIdx.y * BM + wm;
    const size_t col0 = (size_t)blockIdx.x * BN + wn;
    #pragma unroll
    for (int mi = 0; mi < 4; mi++)
        #pragma unroll
        for (int ni = 0; ni < 4; ni++)
            #pragma unroll
            for (int r = 0; r < 4; r++)
                Co[(row0 + mi*16 + quad*4 + r) * (size_t)Ndim + col0 + ni*16 + lr]
                    = acc[mi][ni][r];
}

// ---------------------------------------------------------------------------
// Fused QKV GEMM (exact R0 version): epilogue produces flash-ready tensors.
// Grid (48, 32): bx -> qt = bx>>4 (0=q,1=k,2=v), head h = bx&15;
// by -> b = by>>4, t0 = (by&15)*128.
//   q/k: acc -> LDS [t][136] bf16 -> RoPE -> qb/kb [BH][T][D] bf16.
//   v:   acc -> LDS [d][128] 8-elem units XOR-swizzled by (d&15)
//        -> vt [BH][D][T] bf16.
// ---------------------------------------------------------------------------
__global__ __launch_bounds__(256) void gemm_qkv(
    const ushort* __restrict__ A, const ushort* __restrict__ Bt,
    const float* __restrict__ cosb, const float* __restrict__ sinb,
    ushort* __restrict__ qb, ushort* __restrict__ kbf, ushort* __restrict__ vt)
{
    __shared__ __align__(16) ushort smem[17408];   // 34,816 B
    ushort* As = smem;          // 128*32
    ushort* Bs = smem + 4096;   // 128*32

    const int tid  = threadIdx.x;
    const int lane = tid & 63;
    const int w    = tid >> 6;
    const int wm   = (w >> 1) * 64;
    const int wn   = (w & 1) * 64;
    const int lr   = lane & 15;
    const int quad = lane >> 4;
    const int srow = lane >> 2;
    const int soff = (lane & 3) * 8;

    const int Kdim = C_;
    const ushort* Ablk = A  + (size_t)(blockIdx.y * BM) * Kdim;
    const ushort* Bblk = Bt + (size_t)(blockIdx.x * BN) * Kdim;

    floatx4 acc[4][4];
    #pragma unroll
    for (int i = 0; i < 4; i++)
        #pragma unroll
        for (int j = 0; j < 4; j++)
            acc[i][j] = (floatx4){0.f, 0.f, 0.f, 0.f};

    for (int k0 = 0; k0 < Kdim; k0 += BK) {
        __syncthreads();
        #pragma unroll
        for (int j = 0; j < 2; j++) {
            const int row = w * 32 + j * 16 + srow;
            async16(Ablk + (size_t)row * Kdim + k0 + soff,
                    As + (w * 32 + j * 16) * BK);
            async16(Bblk + (size_t)row * Kdim + k0 + soff,
                    Bs + (w * 32 + j * 16) * BK);
        }
        __syncthreads();

        bf16x8 af[4], bfr[4];
        #pragma unroll
        for (int mi = 0; mi < 4; mi++)
            af[mi] = *(const bf16x8*)(&As[(wm + mi*16 + lr) * BK + quad * 8]);
        #pragma unroll
        for (int ni = 0; ni < 4; ni++)
            bfr[ni] = *(const bf16x8*)(&Bs[(wn + ni*16 + lr) * BK + quad * 8]);
        #pragma unroll
        for (int mi = 0; mi < 4; mi++)
            #pragma unroll
            for (int ni = 0; ni < 4; ni++)
                acc[mi][ni] = mfma_bf16(af[mi], bfr[ni], acc[mi][ni]);
    }

    // ---- epilogue ----
    const int h   = blockIdx.x & 15;
    const int qt  = blockIdx.x >> 4;
    const int b   = blockIdx.y >> 4;
    const int t0g = (blockIdx.y & 15) * 128;
    const int bh  = b * 16 + h;

    __syncthreads();   // all frag reads done before smem reuse

    if (qt < 2) {
        // acc -> LDS [t][136] bf16
        #pragma unroll
        for (int mi = 0; mi < 4; mi++)
            #pragma unroll
            for (int ni = 0; ni < 4; ni++)
                #pragma unroll
                for (int r = 0; r < 4; r++) {
                    const int t = wm + mi*16 + quad*4 + r;
                    const int d = wn + ni*16 + lr;
                    smem[t * 136 + d] = f2bf(acc[mi][ni][r]);
                }
        __syncthreads();

        // readback: thread -> row t = tid>>1, d-chunks [c0,c0+32) and +64
        const int t  = tid >> 1;
        const int c0 = (tid & 1) * 32;
        bf16x8 x1v[4], x2v[4];
        #pragma unroll
        for (int u = 0; u < 4; u++) {
            x1v[u] = *(const bf16x8*)(smem + t * 136 + c0 + u * 8);
            x2v[u] = *(const bf16x8*)(smem + t * 136 + 64 + c0 + u * 8);
        }
        const float4* cp4 = (const float4*)(cosb + (size_t)(t0g + t) * 64 + c0);
        const float4* sp4 = (const float4*)(sinb + (size_t)(t0g + t) * 64 + c0);
        ushort* outp = (qt == 0 ? qb : kbf) + ((size_t)bh * T_ + t0g + t) * D_;
        #pragma unroll
        for (int u = 0; u < 4; u++) {
            float cc[8], ss[8];
            *(float4*)(cc)     = cp4[u * 2];
            *(float4*)(cc + 4) = cp4[u * 2 + 1];
            *(float4*)(ss)     = sp4[u * 2];
            *(float4*)(ss + 4) = sp4[u * 2 + 1];
            ushortx4 lo0, lo1, hi0, hi1;
            #pragma unroll
            for (int e = 0; e < 8; e++) {
                const float x1 = (float)x1v[u][e];
                const float x2 = (float)x2v[u][e];
                const ushort vlo = f2bf(x1 * cc[e] - x2 * ss[e]);
                const ushort vhi = f2bf(x1 * ss[e] + x2 * cc[e]);
                if (e < 4) { lo0[e] = vlo; hi0[e] = vhi; }
                else       { lo1[e-4] = vlo; hi1[e-4] = vhi; }
            }
            *(ushortx4*)(outp + c0 + u*8)          = lo0;
            *(ushortx4*)(outp + c0 + u*8 + 4)      = lo1;
            *(ushortx4*)(outp + 64 + c0 + u*8)     = hi0;
            *(ushortx4*)(outp + 64 + c0 + u*8 + 4) = hi1;
        }
    } else {
        // v: acc -> LDS transposed [d][128], units swizzled by d
        #pragma unroll
        for (int mi = 0; mi < 4; mi++)
            #pragma unroll
            for (int ni = 0; ni < 4; ni++)
                #pragma unroll
                for (int r = 0; r < 4; r++) {
                    const int t = wm + mi*16 + quad*4 + r;
                    const int d = wn + ni*16 + lr;
                    smem[d * 128 + (t & 7) + 8 * ((t >> 3) ^ (d & 15))]
                        = f2bf(acc[mi][ni][r]);
                }
        __syncthreads();

        const int d    = tid >> 1;
        const int half = tid & 1;
        ushort* outp = vt + ((size_t)bh * D_ + d) * T_ + t0g + half * 64;
        #pragma unroll
        for (int u = 0; u < 8; u++) {
            const int gu = half * 8 + u;
            bf16x8 vv = *(const bf16x8*)(smem + d * 128 + 8 * (gu ^ (d & 15)));
            *(bf16x8*)(outp + u * 8) = vv;
        }
    }
}

// ---------------------------------------------------------------------------
// Cooperative causal flash attention, static-shift softmax.
// R6: double-buffered K/V staging with issue-early/drain-late. Per K/V-tile:
//   issue 8 DMAs for tile kt+1 into buf^1 FIRST, compute tile kt from buf,
//   then ONE __syncthreads (its vmcnt(0) drain overlaps the compute phase).
//   Removes the ~500-900 cyc exposed staging latency the old
//   sync->stage->sync structure paid every iteration. LDS 69 KB ->
//   2 blocks/CU (was 4); within-block overlap replaces the lost TLP.
// Output bf16 [M][C] so the proj GEMM consumes it directly.
// ---------------------------------------------------------------------------
__global__ __launch_bounds__(256, 2) void flash_attn(
    const ushort* __restrict__ qb, const ushort* __restrict__ kb,
    const ushort* __restrict__ vt, ushort* __restrict__ attnoutb)
{
    __shared__ __align__(16) ushort kt_s[2][64 * 128];   // [key][d], units ^key
    __shared__ __align__(16) ushort vt_s[2][128 * 64];   // [d][key], units ^d
    __shared__ __align__(16) ushort pl_s[4][16 * 40];    // per-wave P tile

    const int w    = threadIdx.x >> 6;
    const int lane = threadIdx.x & 63;
    const int lr   = lane & 15;
    const int quad = lane >> 4;

    const int bh = blockIdx.x & 31;
    const int m  = 31 - (blockIdx.x >> 5);    // longest key-ranges first
    const int qt = 4 * m + w;
    const int qbase = qt * 16;
    const int nk = m + 1;
    const int bb = bh >> 4, hh = bh & 15;

    const ushort* kbp = kb + (size_t)bh * T_ * D_;
    const ushort* vbp = vt + (size_t)bh * D_ * T_;
    ushort* pl = pl_s[w];

    const int krow4 = lane >> 4;
    const int kunit = lane & 15;
    const int vrow8 = lane >> 3;
    const int vunit = lane & 7;

    bf16x8 qf[4];
    const ushort* qrow = qb + ((size_t)bh * T_ + qbase + lr) * D_ + quad * 8;
    #pragma unroll
    for (int kc = 0; kc < 4; kc++)
        qf[kc] = *(const bf16x8*)(qrow + kc * 32);

    floatx4 o[8];
    #pragma unroll
    for (int dc = 0; dc < 8; dc++) o[dc] = (floatx4){0.f, 0.f, 0.f, 0.f};
    floatx4 lac = (floatx4){0.f, 0.f, 0.f, 0.f};

    const __bf16 one = (__bf16)1.0f;
    const bf16x8 ones = {one, one, one, one, one, one, one, one};
    const float SCL  = 0.08838834764831845f * 1.4426950408889634f;
    const float BIAS = 23.083120654223414f;

    // ---- prologue: stage tile 0 into buf 0 ----
    {
        const int kb0 = 0;
        #pragma unroll
        for (int j = 0; j < 4; j++) {
            const int row = w * 16 + j * 4 + krow4;
            const ushort* gp = kbp + (size_t)(kb0 + row) * D_
                                   + ((kunit ^ (row & 15)) << 3);
            async16(gp, kt_s[0] + (w * 16 + j * 4) * 128);
        }
        #pragma unroll
        for (int j = 0; j < 4; j++) {
            const int row = w * 32 + j * 8 + vrow8;
            const ushort* gp = vbp + (size_t)row * T_ + kb0
                                   + ((vunit ^ (row & 7)) << 3);
            async16(gp, vt_s[0] + (w * 32 + j * 8) * 64);
        }
    }
    __syncthreads();   // drains prologue DMAs (once per block)

    for (int kt = 0; kt < nk; ++kt) {
        const int bsel = kt & 1;
        const int kb0  = kt * 64;

        // ---- issue next tile's DMAs first (fly under compute) ----
        if (kt + 1 < nk) {
            const int kb1 = kb0 + 64;
            #pragma unroll
            for (int j = 0; j < 4; j++) {
                const int row = w * 16 + j * 4 + krow4;
                const ushort* gp = kbp + (size_t)(kb1 + row) * D_
                                       + ((kunit ^ (row & 15)) << 3);
                async16(gp, kt_s[bsel ^ 1] + (w * 16 + j * 4) * 128);
            }
            #pragma unroll
            for (int j = 0; j < 4; j++) {
                const int row = w * 32 + j * 8 + vrow8;
                const ushort* gp = vbp + (size_t)row * T_ + kb1
                                       + ((vunit ^ (row & 7)) << 3);
                async16(gp, vt_s[bsel ^ 1] + (w * 32 + j * 8) * 64);
            }
        }

        // ---- compute tile kt from buf bsel ----
        const ushort* kbuf = kt_s[bsel];
        const ushort* vbuf = vt_s[bsel];

        #pragma unroll
        for (int half = 0; half < 2; ++half) {
            floatx4 st[2];
            #pragma unroll
            for (int jj = 0; jj < 2; ++jj) {
                const int j = half * 2 + jj;
                floatx4 s = (floatx4){0.f, 0.f, 0.f, 0.f};
                const int kl = j * 16 + lr;
                #pragma unroll
                for (int kc = 0; kc < 4; kc++) {
                    bf16x8 af = *(const bf16x8*)(
                        kbuf + kl * 128 + ((((kc << 2) | quad) ^ lr) << 3));
                    s = mfma_bf16(af, qf[kc], s);
                }
                st[jj] = s;
            }
            #pragma unroll
            for (int jj = 0; jj < 2; ++jj) {
                const int j = half * 2 + jj;
                const int kg0 = kb0 + j * 16 + quad * 4;
                float p[4];
                #pragma unroll
                for (int r = 0; r < 4; r++) {
                    float e = __builtin_amdgcn_exp2f(fmaf(st[jj][r], SCL, -BIAS));
                    p[r] = (kg0 + r > qbase + lr) ? 0.f : e;
                }
                uint2 pk;
                pk.x = (uint32_t)f2bf(p[0]) | ((uint32_t)f2bf(p[1]) << 16);
                pk.y = (uint32_t)f2bf(p[2]) | ((uint32_t)f2bf(p[3]) << 16);
                *(uint2*)(pl + lr * 40 + jj * 16 + quad * 4) = pk;
            }
            bf16x8 pf = *(const bf16x8*)(pl + lr * 40 + quad * 8);
            lac = mfma_bf16(pf, ones, lac);
            #pragma unroll
            for (int dc = 0; dc < 8; dc++) {
                const int d = dc * 16 + lr;
                bf16x8 vf = *(const bf16x8*)(
                    vbuf + d * 64 + ((((half << 2) | quad) ^ (lr & 7)) << 3));
                o[dc] = mfma_bf16(pf, vf, o[dc]);
            }
        }

        // ---- one barrier per iter: drains (overlapped) kt+1 DMAs and
        //      certifies all waves done reading buf bsel before iter kt+2
        //      overwrites it ----
        __syncthreads();
    }

    #pragma unroll
    for (int dc = 0; dc < 8; dc++)
        #pragma unroll
        for (int r = 0; r < 4; r++) {
            const int trow = qbase + quad * 4 + r;
            attnoutb[((size_t)(bb * T_ + trow)) * C_ + hh * D_ + dc * 16 + lr]
                = f2bf(o[dc][r] / lac[r]);
        }
}

// ---------------------------------------------------------------------------
extern "C" void kernel_launch(void* const* d_in, const int* in_sizes, int n_in,
                              void* d_out, int out_size, void* d_ws, size_t ws_size,
                              hipStream_t stream)
{
    (void)in_sizes; (void)n_in; (void)out_size; (void)ws_size;
    const float* x     = (const float*)d_in[0];
    const float* cosb  = (const float*)d_in[1];
    const float* sinb  = (const float*)d_in[2];
    const float* Wqkv  = (const float*)d_in[3];
    const float* Wproj = (const float*)d_in[4];
    float* out = (float*)d_out;

    // Workspace (117,440,512 B used):
    //  xb   [M][C] bf16        @ 0          (16,777,216)
    //  Wtq  [3C][C] bf16       @ 16777216   (25,165,824)
    //  Wtp  [C][C] bf16        @ 41943040   ( 8,388,608)
    //  qb   [BH][T][D] bf16    @ 50331648   (16,777,216)
    //  kb   [BH][T][D] bf16    @ 67108864   (16,777,216)
    //  vt   [BH][D][T] bf16    @ 83886080   (16,777,216)
    //  attn [M][C] bf16        @ 100663296  (16,777,216)
    char* ws = (char*)d_ws;
    ushort* xb       = (ushort*)(ws);
    ushort* Wtq      = (ushort*)(ws + 16777216);
    ushort* Wtp      = (ushort*)(ws + 41943040);
    ushort* qb       = (ushort*)(ws + 50331648);
    ushort* kbf      = (ushort*)(ws + 67108864);
    ushort* vt       = (ushort*)(ws + 83886080);
    ushort* attnoutb = (ushort*)(ws + 100663296);

    dim3 tb32(32, 8);
    transpose_w<<<dim3(3 * C_ / 32, C_ / 32), tb32, 0, stream>>>(Wqkv, Wtq, C_, 3 * C_);
    transpose_w<<<dim3(C_ / 32, C_ / 32),     tb32, 0, stream>>>(Wproj, Wtp, C_, C_);
    convert_bf16<<<(M_ * C_ / 4) / 256, 256, 0, stream>>>(x, xb);

    gemm_qkv<<<dim3(3 * C_ / BN, M_ / BM), 256, 0, stream>>>(
        xb, Wtq, cosb, sinb, qb, kbf, vt);

    flash_attn<<<BH_ * 32, 256, 0, stream>>>(qb, kbf, vt, attnoutb);

    gemm_bt<<<dim3(C_ / BN, M_ / BM), 256, 0, stream>>>(attnoutb, Wtp, out, C_, C_);
}